// Round 18
// baseline (119.970 us; speedup 1.0000x reference)
//
#include <hip/hip_runtime.h>
#include <stdint.h>
#include <stddef.h>

typedef _Float16 half_t;
typedef __attribute__((ext_vector_type(8))) _Float16 h16x8;
typedef __attribute__((ext_vector_type(4))) _Float16 h16x4;
typedef __attribute__((ext_vector_type(4))) float f32x4;

#define MFMA16(a, b, c) __builtin_amdgcn_mfma_f32_16x16x32_f16(a, b, c, 0, 0, 0)
#define EXP2(x) __builtin_amdgcn_exp2f(x)

// XOR swizzle: 16B-slot permutation within a 128B row. slot in [0,8).
#define SW(row, slot) ((((slot) ^ ((row) & 7))) * 8)

// async global->LDS, 16B per lane; LDS dest = wave-uniform base + lane*16
__device__ __forceinline__ void gload_lds16(const half_t* g, half_t* l) {
    __builtin_amdgcn_global_load_lds(
        (const __attribute__((address_space(1))) void*)g,
        (__attribute__((address_space(3))) void*)l, 16, 0, 0);
}

// ---------------------------------------------------------------------------
// Kernel 0a: convert x fp32 -> fp16
// ---------------------------------------------------------------------------
__global__ __launch_bounds__(256) void cvt_x_kernel(const float* __restrict__ x,
                                                    half_t* __restrict__ xh, int n8) {
    int i = blockIdx.x * blockDim.x + threadIdx.x;
    if (i >= n8) return;
    const float4* xv = (const float4*)x;
    float4 a = xv[i * 2 + 0];
    float4 b = xv[i * 2 + 1];
    h16x8 o;
    o[0] = (half_t)a.x; o[1] = (half_t)a.y; o[2] = (half_t)a.z; o[3] = (half_t)a.w;
    o[4] = (half_t)b.x; o[5] = (half_t)b.y; o[6] = (half_t)b.z; o[7] = (half_t)b.w;
    ((h16x8*)xh)[i] = o;
}

// ---------------------------------------------------------------------------
// Kernel 0b: transpose + convert W [k][n] fp32 -> Wt [p][n][k] fp16
// ---------------------------------------------------------------------------
__global__ __launch_bounds__(256) void cvt_w_kernel(const float* __restrict__ Wq,
                                                    const float* __restrict__ Wk,
                                                    const float* __restrict__ Wv,
                                                    half_t* __restrict__ Wt) {
    __shared__ float t[32][33];
    const float* W = (blockIdx.z == 0) ? Wq : ((blockIdx.z == 1) ? Wk : Wv);
    int k0 = blockIdx.y * 32, n0 = blockIdx.x * 32;
    int tid = threadIdx.x;
    int r = tid >> 3;          // 0..31
    int c4 = (tid & 7) * 4;    // 0..28
    float4 v = *(const float4*)&W[(size_t)(k0 + r) * 1024 + n0 + c4];
    t[r][c4 + 0] = v.x; t[r][c4 + 1] = v.y; t[r][c4 + 2] = v.z; t[r][c4 + 3] = v.w;
    __syncthreads();
    half_t* o = Wt + (size_t)blockIdx.z * 1024 * 1024 + (size_t)(n0 + r) * 1024 + k0 + c4;
    h16x4 h;
    h[0] = (half_t)t[c4 + 0][r];
    h[1] = (half_t)t[c4 + 1][r];
    h[2] = (half_t)t[c4 + 2][r];
    h[3] = (half_t)t[c4 + 3][r];
    *(h16x4*)o = h;
}

// ---------------------------------------------------------------------------
// Kernel 1: QKV projection GEMM, m97 recipe (global_load_lds 16B, linear LDS,
// pre-swizzled source, XOR-swizzled ds_read). BK=64. grid (8, 32, 3).
// Q stored [bh][s][hd];  K fragment-swizzled for 16x16x32 B-operand;
// V fragment-swizzled Vswz2[bh][kt][d][ks][g][r][8] (kappa-mapped, see attn).
// ---------------------------------------------------------------------------
__global__ __launch_bounds__(256, 3) void gemm_qkv_kernel(
    const half_t* __restrict__ xh,   // [4096][1024]
    const half_t* __restrict__ Wt,   // [3][1024 n][1024 k]
    const float* __restrict__ bq, const float* __restrict__ bk,
    const float* __restrict__ bv,
    half_t* __restrict__ qkv)
{
    const int p = blockIdx.z;
    const float* bias = (p == 0) ? bq : ((p == 1) ? bk : bv);
    const half_t* Wp = Wt + (size_t)p * 1024 * 1024;
    const int n0 = blockIdx.x * 128, m0 = blockIdx.y * 128;

    __shared__ half_t Al[128][64];   // linear 128B rows; source pre-swizzled
    __shared__ half_t Bl[128][64];

    const int tid = threadIdx.x;
    const int lane = tid & 63, wid = tid >> 6;
    const int wm = wid >> 1, wn = wid & 1;
    const int g = lane >> 4, r = lane & 15;

    const int lrow = lane >> 3;                 // 0..7 within issue
    const int swzc = ((lane & 7) ^ lrow) * 8;   // pre-swizzled source col

    f32x4 acc[4][4];
#pragma unroll
    for (int a = 0; a < 4; a++)
#pragma unroll
        for (int c = 0; c < 4; c++) acc[a][c] = (f32x4){0.f, 0.f, 0.f, 0.f};

    for (int k0 = 0; k0 < 1024; k0 += 64) {
        __syncthreads();
#pragma unroll
        for (int j = 0; j < 4; j++) {
            int issue = wid * 4 + j;
            int row = issue * 8 + lrow;
            gload_lds16(&xh[(size_t)(m0 + row) * 1024 + k0 + swzc], &Al[0][0] + issue * 512);
            gload_lds16(&Wp[(size_t)(n0 + row) * 1024 + k0 + swzc], &Bl[0][0] + issue * 512);
        }
        __syncthreads();

#pragma unroll
        for (int t = 0; t < 2; t++) {
            h16x8 af[4], bf[4];
#pragma unroll
            for (int mi = 0; mi < 4; mi++)
                af[mi] = *(const h16x8*)&Al[wm * 64 + mi * 16 + r][SW(r, t * 4 + g)];
#pragma unroll
            for (int ni = 0; ni < 4; ni++)
                bf[ni] = *(const h16x8*)&Bl[wn * 64 + ni * 16 + r][SW(r, t * 4 + g)];
#pragma unroll
            for (int mi = 0; mi < 4; mi++)
#pragma unroll
                for (int ni = 0; ni < 4; ni++)
                    acc[mi][ni] = MFMA16(af[mi], bf[ni], acc[mi][ni]);
        }
    }

    float bn[4];
#pragma unroll
    for (int ni = 0; ni < 4; ni++) bn[ni] = bias[n0 + wn * 64 + ni * 16 + r];

    if (p == 0) {
        // Q: [bh][s][hd] scattered scalar stores
        half_t* outp = qkv;
#pragma unroll
        for (int mi = 0; mi < 4; mi++) {
#pragma unroll
            for (int ni = 0; ni < 4; ni++) {
                int n = n0 + wn * 64 + ni * 16 + r;
                int hq = n >> 6, hd = n & 63;
#pragma unroll
                for (int i = 0; i < 4; i++) {
                    int m = m0 + wm * 64 + mi * 16 + g * 4 + i;
                    int b = m >> 11, s = m & 2047;
                    outp[(((size_t)(b * 16 + hq) * 2048 + s) << 6) + hd] =
                        (half_t)(acc[mi][ni][i] + bn[ni]);
                }
            }
        }
    } else if (p == 1) {
        // K: fragment-swizzled Kswz[bh][kt][kc=mi][t][g'][r'=g*4+i][j]
        half_t* outp = qkv + (size_t)4194304;
        const int kt = ((m0 & 2047) + wm * 64) >> 6;
        const int bK = (m0 + wm * 64) >> 11;
#pragma unroll
        for (int ni = 0; ni < 4; ni++) {
            int n = n0 + wn * 64 + ni * 16 + r;
            int hK = n >> 6, hd = n & 63;
            int tt = hd >> 5, ggk = (hd >> 3) & 3, jK = hd & 7;
            size_t base = (size_t)(bK * 16 + hK) * 131072 + kt * 4096 + tt * 512 + ggk * 128 + jK;
#pragma unroll
            for (int mi = 0; mi < 4; mi++)
#pragma unroll
                for (int i = 0; i < 4; i++)
                    outp[base + mi * 1024 + (g * 4 + i) * 8] =
                        (half_t)(acc[mi][ni][i] + bn[ni]);
        }
    } else {
        // V: Vswz2[bh][kt][d=ni][ks=mi>>1][g][r][8], slot j = (mi&1)*4 + i
        // holds V[kt*64 + ks*32 + kappa(g,j)][d*16+r], kappa=(j>=4)*16+g*4+(j&3)
        half_t* outp = qkv + (size_t)2 * 4194304;
        const int kt = ((m0 & 2047) + wm * 64) >> 6;
        const int bV = (m0 + wm * 64) >> 11;
        const int hV = (n0 + wn * 64) >> 6;
        size_t base = (size_t)(bV * 16 + hV) * 131072 + kt * 4096 + (g * 16 + r) * 8;
#pragma unroll
        for (int ni = 0; ni < 4; ni++) {
#pragma unroll
            for (int mi = 0; mi < 4; mi++) {
                h16x4 pk;
#pragma unroll
                for (int i = 0; i < 4; i++) pk[i] = (half_t)(acc[mi][ni][i] + bn[ni]);
                *(h16x4*)&outp[base + (ni * 2 + (mi >> 1)) * 512 + (mi & 1) * 4] = pk;
            }
        }
    }
}

// ---------------------------------------------------------------------------
// Kernel 2: flash attention, ZERO-LDS, K=32 MFMA, 16 q-rows/wave.
// grid 1024 (XCD-swizzled), block 256 (4 waves) -> 4096 waves = 4 waves/SIMD.
// amdgpu_waves_per_eu(4,4): allocator targets EXACTLY 4 waves/EU (128 VGPR
// budget) instead of squeezing to 64 for an unreachable 8 (R16/R17 lesson).
// sched_barrier(0) after each load group pins the prefetch issue points.
// ---------------------------------------------------------------------------
__global__ __launch_bounds__(256)
__attribute__((amdgpu_waves_per_eu(4, 4)))
void attn_kernel(
    const half_t* __restrict__ Qg,   // [32][2048][64]
    const half_t* __restrict__ Kswz, // [32][32][4][2][4][16][8]
    const half_t* __restrict__ Vswz, // [32][32][4][2][4][16][8] (Vswz2)
    float* __restrict__ out)         // [B][S][1024]
{
    const int tid = threadIdx.x;
    const int lane = tid & 63;
    const int g = lane >> 4, r = lane & 15;

    // XCD-aware remap: all 32 q-blocks of a bh land on one XCD (4 bh/XCD).
    const int bid = blockIdx.x;
    const int xcd = bid & 7;
    const int t_  = bid >> 3;            // 0..127
    const int qblk = t_ & 31;            // 0..31 (64 q-rows each)
    const int bh = xcd + 8 * (t_ >> 5);  // 0..31

    const int b = bh >> 4, h = bh & 15;
    const half_t* Qb = Qg + (size_t)bh * 131072;
    const half_t* Kp = Kswz + (size_t)bh * 131072;
    const half_t* Vp = Vswz + (size_t)bh * 131072;
    const int q0 = qblk * 64 + (tid >> 6) * 16;
    const int lofs = g * 128 + r * 8;    // per-lane fragment offset (halves)

    // hoisted Q fragments, pre-scaled by log2(e)
    h16x8 qf[2];
#pragma unroll
    for (int t = 0; t < 2; t++) {
        qf[t] = *(const h16x8*)&Qb[(size_t)(q0 + r) * 64 + t * 32 + g * 8];
        qf[t] *= (half_t)1.44269504f;
    }

    const h16x8 ones8 = {(half_t)1.f, (half_t)1.f, (half_t)1.f, (half_t)1.f,
                         (half_t)1.f, (half_t)1.f, (half_t)1.f, (half_t)1.f};

    f32x4 o[4], lsum;
#pragma unroll
    for (int d = 0; d < 4; d++) o[d] = (f32x4){0.f, 0.f, 0.f, 0.f};
    lsum = (f32x4){0.f, 0.f, 0.f, 0.f};
    float m_run = 0.f;

    h16x8 kf[8], vf[8];

    auto loadK = [&](int kt) {
#pragma unroll
        for (int kc = 0; kc < 4; kc++)
#pragma unroll
            for (int t = 0; t < 2; t++)
                kf[kc * 2 + t] = *(const h16x8*)&Kp[kt * 4096 + kc * 1024 + t * 512 + lofs];
    };
    auto loadV = [&](int kt) {
#pragma unroll
        for (int dh = 0; dh < 8; dh++)   // dh = d*2 + ks
            vf[dh] = *(const h16x8*)&Vp[kt * 4096 + dh * 512 + lofs];
    };

    loadK(0);

    for (int kt = 0; kt < 32; ++kt) {
        // V for THIS tile: issue pinned here, consumed in PV (far below)
        loadV(kt);
        __builtin_amdgcn_sched_barrier(0);

        // QK^T (swapped): lane holds E[k = kc*16+g*4+i][q = q0+r]
        f32x4 e[4];
        __builtin_amdgcn_s_setprio(1);
#pragma unroll
        for (int kc = 0; kc < 4; kc++) {
            e[kc] = (f32x4){0.f, 0.f, 0.f, 0.f};
#pragma unroll
            for (int t = 0; t < 2; t++)
                e[kc] = MFMA16(kf[kc * 2 + t], qf[t], e[kc]);
        }
        __builtin_amdgcn_s_setprio(0);

        // next tile's K: issue pinned here, consumed next iteration
        loadK((kt + 1) & 31);
        __builtin_amdgcn_sched_barrier(0);

        // ---- softmax (in-lane, exp2 domain) ----
        float t0 = fmaxf(fmaxf(e[0][0], e[0][1]), e[0][2]);
        float t1 = fmaxf(fmaxf(e[0][3], e[1][0]), e[1][1]);
        float t2 = fmaxf(fmaxf(e[1][2], e[1][3]), e[2][0]);
        float t3 = fmaxf(fmaxf(e[2][1], e[2][2]), e[2][3]);
        float t4 = fmaxf(fmaxf(e[3][0], e[3][1]), e[3][2]);
        float tm = fmaxf(fmaxf(t0, t1), fmaxf(fmaxf(t2, t3), fmaxf(t4, e[3][3])));
        tm = fmaxf(tm, __shfl_xor(tm, 16));
        tm = fmaxf(tm, __shfl_xor(tm, 32));

        // unconditional exp with the CURRENT m_run
#pragma unroll
        for (int kc = 0; kc < 4; kc++)
#pragma unroll
            for (int i = 0; i < 4; i++) e[kc][i] = EXP2(e[kc][i] - m_run);

        // rare fix-up: a row's max grew by more than 8 (exp2 domain)
        if (!__all(tm <= m_run + 8.f)) {
            float nm = fmaxf(m_run, tm);
            float sc = EXP2(m_run - nm);
            m_run = nm;
#pragma unroll
            for (int kc = 0; kc < 4; kc++)
#pragma unroll
                for (int i = 0; i < 4; i++) e[kc][i] *= sc;
#pragma unroll
            for (int i = 0; i < 4; i++) {
                float sci = __shfl(sc, (lane & 48) | (g * 4 + i));
                lsum[i] *= sci;
#pragma unroll
                for (int d = 0; d < 4; d++) o[d][i] *= sci;
            }
        }

        // pack: pa[ks] slot (hf*4+i) = P[q=r][k=ks*32+kappa(g,hf*4+i)]
        h16x8 pa[2];
#pragma unroll
        for (int ks = 0; ks < 2; ks++)
#pragma unroll
            for (int hf = 0; hf < 2; hf++)
#pragma unroll
                for (int i = 0; i < 4; i++)
                    pa[ks][hf * 4 + i] = (half_t)e[ks * 2 + hf][i];

        // PV + lsum, full K=32 MFMA (kappa mapping matches Vswz2)
        __builtin_amdgcn_s_setprio(1);
#pragma unroll
        for (int ks = 0; ks < 2; ks++) {
#pragma unroll
            for (int d = 0; d < 4; d++)
                o[d] = MFMA16(pa[ks], vf[d * 2 + ks], o[d]);
            lsum = MFMA16(pa[ks], ones8, lsum);
        }
        __builtin_amdgcn_s_setprio(0);
    }

    // epilogue: lsum holds per-row denominators in o-layout
#pragma unroll
    for (int i = 0; i < 4; i++) {
        float inv = 1.0f / lsum[i];
        int s = q0 + g * 4 + i;
        float* op = out + (size_t)(b * 2048 + s) * 1024 + h * 64 + r;
#pragma unroll
        for (int d = 0; d < 4; d++) op[d * 16] = o[d][i] * inv;
    }
}

// ---------------------------------------------------------------------------
extern "C" void kernel_launch(void* const* d_in, const int* in_sizes, int n_in,
                              void* d_out, int out_size, void* d_ws, size_t ws_size,
                              hipStream_t stream) {
    const float* x  = (const float*)d_in[0];
    const float* Wq = (const float*)d_in[1];
    const float* bq = (const float*)d_in[2];
    const float* Wk = (const float*)d_in[3];
    const float* bk = (const float*)d_in[4];
    const float* Wv = (const float*)d_in[5];
    const float* bv = (const float*)d_in[6];
    float* out = (float*)d_out;

    half_t* xh  = (half_t*)d_ws;
    half_t* Wt  = (half_t*)((char*)d_ws + (size_t)8 * 1024 * 1024);
    half_t* qkv = (half_t*)((char*)d_ws + (size_t)14 * 1024 * 1024);
    half_t* Qh  = qkv;
    half_t* Kh  = qkv + (size_t)4194304;   // Kswz
    half_t* Vth = qkv + (size_t)8388608;   // Vswz2

    cvt_x_kernel<<<2048, 256, 0, stream>>>(x, xh, 524288);
    cvt_w_kernel<<<dim3(32, 32, 3), 256, 0, stream>>>(Wq, Wk, Wv, Wt);
    gemm_qkv_kernel<<<dim3(8, 32, 3), 256, 0, stream>>>(xh, Wt, bq, bk, bv, qkv);
    attn_kernel<<<1024, 256, 0, stream>>>(Qh, Kh, Vth, out);
}

// Round 19
// 97.889 us; speedup vs baseline: 1.2256x; 1.2256x over previous
//
#include <hip/hip_runtime.h>
#include <stdint.h>
#include <stddef.h>

typedef _Float16 half_t;
typedef __attribute__((ext_vector_type(8))) _Float16 h16x8;
typedef __attribute__((ext_vector_type(4))) _Float16 h16x4;
typedef __attribute__((ext_vector_type(4))) float f32x4;

#define MFMA16(a, b, c) __builtin_amdgcn_mfma_f32_16x16x32_f16(a, b, c, 0, 0, 0)
#define EXP2(x) __builtin_amdgcn_exp2f(x)

// XOR swizzle: 16B-slot permutation within a 128B row. slot in [0,8).
#define SW(row, slot) ((((slot) ^ ((row) & 7))) * 8)

// async global->LDS, 16B per lane; LDS dest = wave-uniform base + lane*16
__device__ __forceinline__ void gload_lds16(const half_t* g, half_t* l) {
    __builtin_amdgcn_global_load_lds(
        (const __attribute__((address_space(1))) void*)g,
        (__attribute__((address_space(3))) void*)l, 16, 0, 0);
}

// ---------------------------------------------------------------------------
// Kernel 0a: convert x fp32 -> fp16
// ---------------------------------------------------------------------------
__global__ __launch_bounds__(256) void cvt_x_kernel(const float* __restrict__ x,
                                                    half_t* __restrict__ xh, int n8) {
    int i = blockIdx.x * blockDim.x + threadIdx.x;
    if (i >= n8) return;
    const float4* xv = (const float4*)x;
    float4 a = xv[i * 2 + 0];
    float4 b = xv[i * 2 + 1];
    h16x8 o;
    o[0] = (half_t)a.x; o[1] = (half_t)a.y; o[2] = (half_t)a.z; o[3] = (half_t)a.w;
    o[4] = (half_t)b.x; o[5] = (half_t)b.y; o[6] = (half_t)b.z; o[7] = (half_t)b.w;
    ((h16x8*)xh)[i] = o;
}

// ---------------------------------------------------------------------------
// Kernel 0b: transpose + convert W [k][n] fp32 -> Wt [p][n][k] fp16
// ---------------------------------------------------------------------------
__global__ __launch_bounds__(256) void cvt_w_kernel(const float* __restrict__ Wq,
                                                    const float* __restrict__ Wk,
                                                    const float* __restrict__ Wv,
                                                    half_t* __restrict__ Wt) {
    __shared__ float t[32][33];
    const float* W = (blockIdx.z == 0) ? Wq : ((blockIdx.z == 1) ? Wk : Wv);
    int k0 = blockIdx.y * 32, n0 = blockIdx.x * 32;
    int tid = threadIdx.x;
    int r = tid >> 3;          // 0..31
    int c4 = (tid & 7) * 4;    // 0..28
    float4 v = *(const float4*)&W[(size_t)(k0 + r) * 1024 + n0 + c4];
    t[r][c4 + 0] = v.x; t[r][c4 + 1] = v.y; t[r][c4 + 2] = v.z; t[r][c4 + 3] = v.w;
    __syncthreads();
    half_t* o = Wt + (size_t)blockIdx.z * 1024 * 1024 + (size_t)(n0 + r) * 1024 + k0 + c4;
    h16x4 h;
    h[0] = (half_t)t[c4 + 0][r];
    h[1] = (half_t)t[c4 + 1][r];
    h[2] = (half_t)t[c4 + 2][r];
    h[3] = (half_t)t[c4 + 3][r];
    *(h16x4*)o = h;
}

// ---------------------------------------------------------------------------
// Kernel 1: QKV projection GEMM, m97 recipe (global_load_lds 16B, linear LDS,
// pre-swizzled source, XOR-swizzled ds_read). BK=64. grid (8, 32, 3).
// ---------------------------------------------------------------------------
__global__ __launch_bounds__(256, 3) void gemm_qkv_kernel(
    const half_t* __restrict__ xh,   // [4096][1024]
    const half_t* __restrict__ Wt,   // [3][1024 n][1024 k]
    const float* __restrict__ bq, const float* __restrict__ bk,
    const float* __restrict__ bv,
    half_t* __restrict__ qkv)
{
    const int p = blockIdx.z;
    const float* bias = (p == 0) ? bq : ((p == 1) ? bk : bv);
    const half_t* Wp = Wt + (size_t)p * 1024 * 1024;
    const int n0 = blockIdx.x * 128, m0 = blockIdx.y * 128;

    __shared__ half_t Al[128][64];   // linear 128B rows; source pre-swizzled
    __shared__ half_t Bl[128][64];

    const int tid = threadIdx.x;
    const int lane = tid & 63, wid = tid >> 6;
    const int wm = wid >> 1, wn = wid & 1;
    const int g = lane >> 4, r = lane & 15;

    const int lrow = lane >> 3;                 // 0..7 within issue
    const int swzc = ((lane & 7) ^ lrow) * 8;   // pre-swizzled source col

    f32x4 acc[4][4];
#pragma unroll
    for (int a = 0; a < 4; a++)
#pragma unroll
        for (int c = 0; c < 4; c++) acc[a][c] = (f32x4){0.f, 0.f, 0.f, 0.f};

    for (int k0 = 0; k0 < 1024; k0 += 64) {
        __syncthreads();
#pragma unroll
        for (int j = 0; j < 4; j++) {
            int issue = wid * 4 + j;
            int row = issue * 8 + lrow;
            gload_lds16(&xh[(size_t)(m0 + row) * 1024 + k0 + swzc], &Al[0][0] + issue * 512);
            gload_lds16(&Wp[(size_t)(n0 + row) * 1024 + k0 + swzc], &Bl[0][0] + issue * 512);
        }
        __syncthreads();

#pragma unroll
        for (int t = 0; t < 2; t++) {
            h16x8 af[4], bf[4];
#pragma unroll
            for (int mi = 0; mi < 4; mi++)
                af[mi] = *(const h16x8*)&Al[wm * 64 + mi * 16 + r][SW(r, t * 4 + g)];
#pragma unroll
            for (int ni = 0; ni < 4; ni++)
                bf[ni] = *(const h16x8*)&Bl[wn * 64 + ni * 16 + r][SW(r, t * 4 + g)];
#pragma unroll
            for (int mi = 0; mi < 4; mi++)
#pragma unroll
                for (int ni = 0; ni < 4; ni++)
                    acc[mi][ni] = MFMA16(af[mi], bf[ni], acc[mi][ni]);
        }
    }

    float bn[4];
#pragma unroll
    for (int ni = 0; ni < 4; ni++) bn[ni] = bias[n0 + wn * 64 + ni * 16 + r];

    if (p == 0) {
        // Q: [bh][s][hd] scattered scalar stores
        half_t* outp = qkv;
#pragma unroll
        for (int mi = 0; mi < 4; mi++) {
#pragma unroll
            for (int ni = 0; ni < 4; ni++) {
                int n = n0 + wn * 64 + ni * 16 + r;
                int hq = n >> 6, hd = n & 63;
#pragma unroll
                for (int i = 0; i < 4; i++) {
                    int m = m0 + wm * 64 + mi * 16 + g * 4 + i;
                    int b = m >> 11, s = m & 2047;
                    outp[(((size_t)(b * 16 + hq) * 2048 + s) << 6) + hd] =
                        (half_t)(acc[mi][ni][i] + bn[ni]);
                }
            }
        }
    } else if (p == 1) {
        // K: fragment-swizzled Kswz[bh][kt][kc=mi][t][g'][r'=g*4+i][j]
        half_t* outp = qkv + (size_t)4194304;
        const int kt = ((m0 & 2047) + wm * 64) >> 6;
        const int bK = (m0 + wm * 64) >> 11;
#pragma unroll
        for (int ni = 0; ni < 4; ni++) {
            int n = n0 + wn * 64 + ni * 16 + r;
            int hK = n >> 6, hd = n & 63;
            int tt = hd >> 5, ggk = (hd >> 3) & 3, jK = hd & 7;
            size_t base = (size_t)(bK * 16 + hK) * 131072 + kt * 4096 + tt * 512 + ggk * 128 + jK;
#pragma unroll
            for (int mi = 0; mi < 4; mi++)
#pragma unroll
                for (int i = 0; i < 4; i++)
                    outp[base + mi * 1024 + (g * 4 + i) * 8] =
                        (half_t)(acc[mi][ni][i] + bn[ni]);
        }
    } else {
        // V: fragment-swizzled Vswz[bh][kt][d=ni][ks][g'][r][j], packed h16x4
        half_t* outp = qkv + (size_t)2 * 4194304;
        const int kt = ((m0 & 2047) + wm * 64) >> 6;
        const int bV = (m0 + wm * 64) >> 11;
        const int jv = (g & 1) * 4, gv_hi = g >> 1;
#pragma unroll
        for (int ni = 0; ni < 4; ni++) {
            int n = n0 + wn * 64 + ni * 16 + r;
            int hV = n >> 6;
            size_t hb = (size_t)(bV * 16 + hV) * 131072 + kt * 4096 + ni * 1024;
#pragma unroll
            for (int mi = 0; mi < 4; mi++) {
                int ks = mi >> 1, ggv = (mi & 1) * 2 + gv_hi;
                h16x4 pk;
#pragma unroll
                for (int i = 0; i < 4; i++) pk[i] = (half_t)(acc[mi][ni][i] + bn[ni]);
                *(h16x4*)&outp[hb + ks * 512 + ggv * 128 + r * 8 + jv] = pk;
            }
        }
    }
}

// ---------------------------------------------------------------------------
// Kernel 2: flash attention. Barrier-free, coalesced direct-global K/V,
// 2-tile pipeline (single V buffer). Body order puts QKT[t+1] between
// P-write[t] and PV[t] so the lgkmcnt(0) is pre-drained. MFMA lsum
// denominator; s_setprio around MFMA clusters.  [R13 best: 54.0 us]
// ---------------------------------------------------------------------------
__global__ __launch_bounds__(256, 2) void attn_kernel(
    const half_t* __restrict__ Qg,   // [32][2048][64]
    const half_t* __restrict__ Kswz, // [32][32][4][2][4][16][8]
    const half_t* __restrict__ Vswz, // [32][32][4][2][4][16][8]
    float* __restrict__ out)         // [B][S][1024]
{
    __shared__ half_t Pl[4][32][64];    // per-wave P tile (16 KB)

    const int tid = threadIdx.x;
    const int lane = tid & 63, wid = tid >> 6;
    const int g = lane >> 4, r = lane & 15;

    // XCD-aware remap: all 16 q-blocks of a bh land on one XCD (4 bh/XCD).
    const int bid = blockIdx.x;
    const int xcd = bid & 7;
    const int t_  = bid >> 3;            // 0..63
    const int qblk = t_ & 15;            // 0..15
    const int bh = xcd + 8 * (t_ >> 4);  // 0..31

    const int b = bh >> 4, h = bh & 15;
    const half_t* Qb = Qg + (size_t)bh * 131072;
    const half_t* Kp = Kswz + (size_t)bh * 131072;
    const half_t* Vp = Vswz + (size_t)bh * 131072;
    const int q0 = qblk * 128 + wid * 32;
    const int lofs = g * 128 + r * 8;    // per-lane fragment offset (halves)

    // hoisted Q fragments (2 q-groups), pre-scaled by log2(e)
    h16x8 qf[2][2];
#pragma unroll
    for (int qg = 0; qg < 2; qg++)
#pragma unroll
        for (int t = 0; t < 2; t++) {
            qf[qg][t] = *(const h16x8*)&Qb[(size_t)(q0 + qg * 16 + r) * 64 + t * 32 + g * 8];
            qf[qg][t] *= (half_t)1.44269504f;
        }

    const h16x8 ones = {(half_t)1.f, (half_t)1.f, (half_t)1.f, (half_t)1.f,
                        (half_t)1.f, (half_t)1.f, (half_t)1.f, (half_t)1.f};

    f32x4 o[2][4], lsum[2];
#pragma unroll
    for (int qg = 0; qg < 2; qg++) {
#pragma unroll
        for (int d = 0; d < 4; d++) o[qg][d] = (f32x4){0.f, 0.f, 0.f, 0.f};
        lsum[qg] = (f32x4){0.f, 0.f, 0.f, 0.f};
    }
    float m_run[2] = {0.f, 0.f};

    h16x8 kf[8], vf[8];

    auto loadK = [&](int kt) {
#pragma unroll
        for (int kc = 0; kc < 4; kc++)
#pragma unroll
            for (int t = 0; t < 2; t++)
                kf[kc * 2 + t] = *(const h16x8*)&Kp[kt * 4096 + kc * 1024 + t * 512 + lofs];
    };
    auto loadV = [&](int kt) {
#pragma unroll
        for (int d = 0; d < 4; d++)
#pragma unroll
            for (int ks = 0; ks < 2; ks++)
                vf[d * 2 + ks] = *(const h16x8*)&Vp[kt * 4096 + d * 1024 + ks * 512 + lofs];
    };

    auto QKT = [&](f32x4 (&e)[2][4]) {
        __builtin_amdgcn_s_setprio(1);
#pragma unroll
        for (int kc = 0; kc < 4; kc++) {
            e[0][kc] = (f32x4){0.f, 0.f, 0.f, 0.f};
            e[1][kc] = (f32x4){0.f, 0.f, 0.f, 0.f};
#pragma unroll
            for (int t = 0; t < 2; t++) {
                e[0][kc] = MFMA16(kf[kc * 2 + t], qf[0][t], e[0][kc]);
                e[1][kc] = MFMA16(kf[kc * 2 + t], qf[1][t], e[1][kc]);
            }
        }
        __builtin_amdgcn_s_setprio(0);
    };

    auto SOFTMAX_P = [&](f32x4 (&e)[2][4]) {
#pragma unroll
        for (int qg = 0; qg < 2; qg++) {
            float t0 = fmaxf(fmaxf(e[qg][0][0], e[qg][0][1]), e[qg][0][2]);
            float t1 = fmaxf(fmaxf(e[qg][0][3], e[qg][1][0]), e[qg][1][1]);
            float t2 = fmaxf(fmaxf(e[qg][1][2], e[qg][1][3]), e[qg][2][0]);
            float t3 = fmaxf(fmaxf(e[qg][2][1], e[qg][2][2]), e[qg][2][3]);
            float t4 = fmaxf(fmaxf(e[qg][3][0], e[qg][3][1]), e[qg][3][2]);
            float tm = fmaxf(fmaxf(t0, t1), fmaxf(fmaxf(t2, t3), fmaxf(t4, e[qg][3][3])));
            tm = fmaxf(tm, __shfl_xor(tm, 16));
            tm = fmaxf(tm, __shfl_xor(tm, 32));

            // unconditional exp with the CURRENT m_run
#pragma unroll
            for (int kc = 0; kc < 4; kc++)
#pragma unroll
                for (int i = 0; i < 4; i++) e[qg][kc][i] = EXP2(e[qg][kc][i] - m_run[qg]);

            // rare fix-up: a row's max grew by more than 8 (exp2 domain)
            if (!__all(tm <= m_run[qg] + 8.f)) {
                float nm = fmaxf(m_run[qg], tm);
                float sc = EXP2(m_run[qg] - nm);
                m_run[qg] = nm;
#pragma unroll
                for (int kc = 0; kc < 4; kc++)
#pragma unroll
                    for (int i = 0; i < 4; i++) e[qg][kc][i] *= sc;
#pragma unroll
                for (int i = 0; i < 4; i++) {
                    float sci = __shfl(sc, (lane & 48) | (g * 4 + i));
                    lsum[qg][i] *= sci;
#pragma unroll
                    for (int d = 0; d < 4; d++) o[qg][d][i] *= sci;
                }
            }

            // P -> per-wave LDS (swizzled b64 writes)
#pragma unroll
            for (int kc = 0; kc < 4; kc++) {
                h16x4 pk;
#pragma unroll
                for (int i = 0; i < 4; i++) pk[i] = (half_t)e[qg][kc][i];
                *(h16x4*)&Pl[wid][qg * 16 + r][SW(r, 2 * kc + (g >> 1)) + (g & 1) * 4] = pk;
            }
        }
    };

    auto PV = [&]() {
        asm volatile("s_waitcnt lgkmcnt(0)" ::: "memory");
        __builtin_amdgcn_sched_barrier(0);
        __builtin_amdgcn_s_setprio(1);
#pragma unroll
        for (int ks = 0; ks < 2; ks++) {
            h16x8 pf0 = *(const h16x8*)&Pl[wid][r][SW(r, ks * 4 + g)];
            h16x8 pf1 = *(const h16x8*)&Pl[wid][16 + r][SW(r, ks * 4 + g)];
#pragma unroll
            for (int d = 0; d < 4; d++) {
                o[0][d] = MFMA16(pf0, vf[d * 2 + ks], o[0][d]);
                o[1][d] = MFMA16(pf1, vf[d * 2 + ks], o[1][d]);
            }
            // denominator: lsum += P @ ones (full 32-k sum, o-layout)
            lsum[0] = MFMA16(pf0, ones, lsum[0]);
            lsum[1] = MFMA16(pf1, ones, lsum[1]);
        }
        __builtin_amdgcn_s_setprio(0);
    };

    // prologue: e for tile 0
    f32x4 eA[2][4], eB[2][4];
    loadK(0);
    QKT(eA);
    loadK(1);

    for (int kt = 0; kt < 32; kt += 2) {
        // ---- tile kt (state in eA) ----
        loadV(kt);                  // V latency covered by softmax
        SOFTMAX_P(eA);              // ends with P ds_writes
        QKT(eB);                    // tile kt+1 MFMAs drain the ds_write latency
        loadK((kt + 2) & 31);       // kf free after QKT; wraps (harmless)
        PV();                       // lgkmcnt(0) nearly free
        // ---- tile kt+1 (state in eB) ----
        loadV(kt + 1);
        SOFTMAX_P(eB);
        QKT(eA);                    // tile kt+2 (garbage on last pair, unused)
        loadK((kt + 3) & 31);
        PV();
    }

    // epilogue: lsum already holds per-row denominators in o-layout
#pragma unroll
    for (int qg = 0; qg < 2; qg++)
#pragma unroll
        for (int i = 0; i < 4; i++) {
            float inv = 1.0f / lsum[qg][i];
            int s = q0 + qg * 16 + g * 4 + i;
            float* op = out + (size_t)(b * 2048 + s) * 1024 + h * 64 + r;
#pragma unroll
            for (int d = 0; d < 4; d++) op[d * 16] = o[qg][d][i] * inv;
        }
}

// ---------------------------------------------------------------------------
extern "C" void kernel_launch(void* const* d_in, const int* in_sizes, int n_in,
                              void* d_out, int out_size, void* d_ws, size_t ws_size,
                              hipStream_t stream) {
    const float* x  = (const float*)d_in[0];
    const float* Wq = (const float*)d_in[1];
    const float* bq = (const float*)d_in[2];
    const float* Wk = (const float*)d_in[3];
    const float* bk = (const float*)d_in[4];
    const float* Wv = (const float*)d_in[5];
    const float* bv = (const float*)d_in[6];
    float* out = (float*)d_out;

    half_t* xh  = (half_t*)d_ws;
    half_t* Wt  = (half_t*)((char*)d_ws + (size_t)8 * 1024 * 1024);
    half_t* qkv = (half_t*)((char*)d_ws + (size_t)14 * 1024 * 1024);
    half_t* Qh  = qkv;
    half_t* Kh  = qkv + (size_t)4194304;   // Kswz
    half_t* Vth = qkv + (size_t)8388608;   // Vswz

    cvt_x_kernel<<<2048, 256, 0, stream>>>(x, xh, 524288);
    cvt_w_kernel<<<dim3(32, 32, 3), 256, 0, stream>>>(Wq, Wk, Wv, Wt);
    gemm_qkv_kernel<<<dim3(8, 32, 3), 256, 0, stream>>>(xh, Wt, bq, bk, bv, qkv);
    attn_kernel<<<dim3(512), 256, 0, stream>>>(Qh, Kh, Vth, out);
}